// Round 3
// 191.235 us; speedup vs baseline: 1.1240x; 1.1240x over previous
//
#include <hip/hip_runtime.h>
#include <hip/hip_bf16.h>

#define N 4096
#define C 512

typedef __attribute__((ext_vector_type(8))) short bf16x8;
typedef __attribute__((ext_vector_type(8))) short s16x8;
typedef __attribute__((ext_vector_type(4))) float f32x4;

__device__ inline float bf2f(__hip_bfloat16 h) { return __bfloat162float(h); }

__device__ inline void gload16(const void* g, void* l) {
    __builtin_amdgcn_global_load_lds(
        (__attribute__((address_space(1))) void*)(g),
        (__attribute__((address_space(3))) void*)(l),
        16, 0, 0);
}

// ================= kernel 1: single-pass paired prep ==========================
// 512 blocks x 256 threads. pair = b>>8 (0: v&pt -> dv, 1: t&pv -> dt),
// chunk = b&255 (16 rows). Wave w owns rows chunk*16 + w*4 .. +3.
__global__ __launch_bounds__(256) void k_prep(
    const float* __restrict__ s0, const float* __restrict__ s1f,
    const float* __restrict__ s2f, const float* __restrict__ s3,
    __hip_bfloat16* __restrict__ ws_hi0, long mat_stride,
    float* __restrict__ dv, float* __restrict__ dt,
    float* __restrict__ colsum, float* __restrict__ colsq)
{
    __shared__ float sa[4][512];
    __shared__ float sq[4][512];

    const int b = blockIdx.x;
    const int tid = threadIdx.x;
    const int lane = tid & 63;
    const int w = tid >> 6;

    const int pair = b >> 8;
    const int chunk = b & 255;
    const float* X = pair ? s1f : s0;        // t : v
    const float* B = pair ? s2f : s3;        // pv : pt
    const int mX = pair ? 1 : 0;
    const int mB = pair ? 2 : 3;
    __hip_bfloat16* hiX = ws_hi0 + (long)mX * mat_stride;
    __hip_bfloat16* loX = hiX + (long)N * C;
    __hip_bfloat16* hiB = ws_hi0 + (long)mB * mat_stride;
    __hip_bfloat16* loB = hiB + (long)N * C;
    float* dout = pair ? dt : dv;

    float aX[8], qX[8], aB[8], qB[8];
    for (int e = 0; e < 8; e++) { aX[e] = 0.f; qX[e] = 0.f; aB[e] = 0.f; qB[e] = 0.f; }

    const int row0 = chunk * 16 + w * 4;
    for (int i = 0; i < 4; i++) {
        const int row = row0 + i;
        const float4* x4 = (const float4*)(X + (size_t)row * C);
        const float4* b4 = (const float4*)(B + (size_t)row * C);
        float4 x0 = x4[lane * 2], x1 = x4[lane * 2 + 1];
        float4 b0 = b4[lane * 2], b1 = b4[lane * 2 + 1];

        float ss  = x0.x*x0.x + x0.y*x0.y + x0.z*x0.z + x0.w*x0.w
                  + x1.x*x1.x + x1.y*x1.y + x1.z*x1.z + x1.w*x1.w;
        float ssb = b0.x*b0.x + b0.y*b0.y + b0.z*b0.z + b0.w*b0.w
                  + b1.x*b1.x + b1.y*b1.y + b1.z*b1.z + b1.w*b1.w;
        float dot = x0.x*b0.x + x0.y*b0.y + x0.z*b0.z + x0.w*b0.w
                  + x1.x*b1.x + x1.y*b1.y + x1.z*b1.z + x1.w*b1.w;
        for (int o = 1; o < 64; o <<= 1) {       // 3 independent chains, interleaved
            ss  += __shfl_xor(ss, o);
            ssb += __shfl_xor(ssb, o);
            dot += __shfl_xor(dot, o);
        }
        float scX = 1.0f / fmaxf(sqrtf(ss), 1e-12f);
        float scB = 1.0f / fmaxf(sqrtf(ssb), 1e-12f);
        if (lane == 0) dout[row] = dot * scX * scB;

        float yx[8] = { x0.x*scX, x0.y*scX, x0.z*scX, x0.w*scX,
                        x1.x*scX, x1.y*scX, x1.z*scX, x1.w*scX };
        float yb[8] = { b0.x*scB, b0.y*scB, b0.z*scB, b0.w*scB,
                        b1.x*scB, b1.y*scB, b1.z*scB, b1.w*scB };
        __hip_bfloat16 hvx[8], lvx[8], hvb[8], lvb[8];
        for (int e = 0; e < 8; e++) {
            hvx[e] = __float2bfloat16(yx[e]);
            lvx[e] = __float2bfloat16(yx[e] - bf2f(hvx[e]));
            aX[e] += yx[e]; qX[e] += yx[e] * yx[e];
            hvb[e] = __float2bfloat16(yb[e]);
            lvb[e] = __float2bfloat16(yb[e] - bf2f(hvb[e]));
            aB[e] += yb[e]; qB[e] += yb[e] * yb[e];
        }
        size_t base = (size_t)row * C + lane * 8;
        *(s16x8*)(hiX + base) = *(s16x8*)hvx;
        *(s16x8*)(loX + base) = *(s16x8*)lvx;
        *(s16x8*)(hiB + base) = *(s16x8*)hvb;
        *(s16x8*)(loB + base) = *(s16x8*)lvb;
    }

    for (int e = 0; e < 8; e++) { sa[w][lane*8+e] = aX[e]; sq[w][lane*8+e] = qX[e]; }
    __syncthreads();
    for (int c = tid; c < 512; c += 256) {
        atomicAdd(&colsum[mX * 512 + c], sa[0][c] + sa[1][c] + sa[2][c] + sa[3][c]);
        atomicAdd(&colsq [mX * 512 + c], sq[0][c] + sq[1][c] + sq[2][c] + sq[3][c]);
    }
    __syncthreads();
    for (int e = 0; e < 8; e++) { sa[w][lane*8+e] = aB[e]; sq[w][lane*8+e] = qB[e]; }
    __syncthreads();
    for (int c = tid; c < 512; c += 256) {
        atomicAdd(&colsum[mB * 512 + c], sa[0][c] + sa[1][c] + sa[2][c] + sa[3][c]);
        atomicAdd(&colsq [mB * 512 + c], sq[0][c] + sq[1][c] + sq[2][c] + sq[3][c]);
    }
}

// ================= kernel 2: fused split-GEMM, 256^2 tile, 4-phase pipeline ===
// ROUND-2 DE-RISK of the 4-phase 256^2 schedule (vs round-0/1 version that
// killed the container twice):
//   - LDS is now EXACTLY 128 KiB (verified-territory max, m194-m201): sdiag and
//     sred are an epilogue-only OVERLAY on the staging space; diag is loaded in
//     the epilogue (256 L2-hot floats).
//   - K-loop is '#pragma unroll 1' over 8 trips with a manual 2x body (literal
//     buffer index) -> ~200 MFMAs of code instead of ~1500 (compile time + I$).
//   - Schedule unchanged: per K-tile 4 phases, each {ds_read quad || gload_lds
//     t+1 -> other buf; s_barrier; lgkmcnt(0); setprio(1); 24 MFMA; setprio(0);
//     s_barrier}; prefetch issued phases 0-1; single vmcnt(0) at K-tile end.
//   - XOR k-chunk swizzle unchanged (verified SQ_LDS_BANK_CONFLICT == 0).
//   - Numerics bit-identical: hh/hl/lh order per acc element per K-step.
#define PLANE 8192   // elems per 256x32 bf16 plane (16 KiB)
#define LIDX(BUF, ROW, COL) ((BUF) * PLANE + (ROW) * 32 + (COL))

__global__ __launch_bounds__(512, 2) void k_gemm(
    const __hip_bfloat16* __restrict__ h0, const __hip_bfloat16* __restrict__ l0,
    const __hip_bfloat16* __restrict__ h1, const __hip_bfloat16* __restrict__ l1,
    const __hip_bfloat16* __restrict__ h2, const __hip_bfloat16* __restrict__ l2,
    const __hip_bfloat16* __restrict__ h3, const __hip_bfloat16* __restrict__ l3,
    const float* __restrict__ dv, const float* __restrict__ dt,
    float* __restrict__ row_ev, float* __restrict__ row_et,
    float* __restrict__ row_cv, float* __restrict__ row_ct)
{
    __shared__ __align__(16) char smem[131072];   // 128 KiB exactly
    __hip_bfloat16* SAh = (__hip_bfloat16*)smem;  // [2][256][32]
    __hip_bfloat16* SAl = SAh + 2 * PLANE;
    __hip_bfloat16* SBh = SAh + 4 * PLANE;
    __hip_bfloat16* SBl = SAh + 6 * PLANE;

    const int z = blockIdx.z;
    const __hip_bfloat16* Ah = z ? h1 : h0;
    const __hip_bfloat16* Al = z ? l1 : l0;
    const __hip_bfloat16* Bh = z ? h2 : h3;
    const __hip_bfloat16* Bl = z ? l2 : l3;
    const float* diag = z ? dt : dv;
    float* row_e = z ? row_et : row_ev;
    float* row_c = z ? row_ct : row_cv;

    const int tid = threadIdx.x;
    const int lane = tid & 63;
    const int w = tid >> 6;
    const int wy = w >> 2, wx = w & 3;     // 2 row-halves x 4 col-quarters
    const int bm = blockIdx.x * 256;
    const int bn = blockIdx.y * 256;

    // ---- staging geometry: slot s covers row s>>2, k-chunk s&3 (16B each).
    // LDS dest offset = s*16 B  -> linear in lane within each wave (gload_lds req).
    const int s0i = tid, s1i = tid + 512;
    const int r0 = s0i >> 2, q0 = s0i & 3;
    const int r1 = s1i >> 2, q1 = s1i & 3;
    const int g0 = (q0 ^ ((r0 >> 1) & 3)) * 8;   // swizzled global k-chunk
    const int g1 = (q1 ^ ((r1 >> 1) & 3)) * 8;
    const size_t aoff0 = (size_t)(bm + r0) * C + g0;
    const size_t aoff1 = (size_t)(bm + r1) * C + g1;
    const size_t boff0 = (size_t)(bn + r0) * C + g0;
    const size_t boff1 = (size_t)(bn + r1) * C + g1;
    const int d0 = s0i * 8, d1 = s1i * 8;        // LDS elem offsets within plane

    const int fr = lane & 15;
    const int pcs = ((lane >> 4) ^ ((fr >> 1) & 3)) * 8;  // swizzled read k

    f32x4 acc[8][4];
    #pragma unroll
    for (int i = 0; i < 8; i++)
        #pragma unroll
        for (int j = 0; j < 4; j++)
            acc[i][j] = (f32x4){0.f, 0.f, 0.f, 0.f};

    // ---- prologue: stage K-tile 0 into buffer 0
    gload16(Ah + aoff0, SAh + d0); gload16(Ah + aoff1, SAh + d1);
    gload16(Al + aoff0, SAl + d0); gload16(Al + aoff1, SAl + d1);
    gload16(Bh + boff0, SBh + d0); gload16(Bh + boff1, SBh + d1);
    gload16(Bl + boff0, SBl + d0); gload16(Bl + boff1, SBl + d1);
    __syncthreads();

#define MFMA1(d, a, b) d = __builtin_amdgcn_mfma_f32_16x16x32_bf16(a, b, d, 0, 0, 0)
    // 24 MFMAs: passes hh, hl, lh over a row-pair x 4 col-frags. acc reuse
    // distance = 8 (no back-to-back dependent MFMAs).
#define QUAD(i0, i1, A0H, A0L, A1H, A1L) \
    MFMA1(acc[i0][0], A0H, bh[0]); MFMA1(acc[i0][1], A0H, bh[1]); \
    MFMA1(acc[i0][2], A0H, bh[2]); MFMA1(acc[i0][3], A0H, bh[3]); \
    MFMA1(acc[i1][0], A1H, bh[0]); MFMA1(acc[i1][1], A1H, bh[1]); \
    MFMA1(acc[i1][2], A1H, bh[2]); MFMA1(acc[i1][3], A1H, bh[3]); \
    MFMA1(acc[i0][0], A0H, bl[0]); MFMA1(acc[i0][1], A0H, bl[1]); \
    MFMA1(acc[i0][2], A0H, bl[2]); MFMA1(acc[i0][3], A0H, bl[3]); \
    MFMA1(acc[i1][0], A1H, bl[0]); MFMA1(acc[i1][1], A1H, bl[1]); \
    MFMA1(acc[i1][2], A1H, bl[2]); MFMA1(acc[i1][3], A1H, bl[3]); \
    MFMA1(acc[i0][0], A0L, bh[0]); MFMA1(acc[i0][1], A0L, bh[1]); \
    MFMA1(acc[i0][2], A0L, bh[2]); MFMA1(acc[i0][3], A0L, bh[3]); \
    MFMA1(acc[i1][0], A1L, bh[0]); MFMA1(acc[i1][1], A1L, bh[1]); \
    MFMA1(acc[i1][2], A1L, bh[2]); MFMA1(acc[i1][3], A1L, bh[3])

// One K-tile: read buffer RB (literal 0/1), prefetch K-tile TCUR+1 into 1-RB.
#define KBODY(RB, TCUR)                                                          \
    {                                                                            \
        const size_t kn = (size_t)((TCUR) + 1) * 32;                             \
        const int fpl = (1 - (RB)) * PLANE;                                      \
        const bool pf = ((TCUR) < NT - 1);                                       \
        bf16x8 bh[4], bl[4];                                                     \
        { /* phase 0: b-frags + a-quad0 || stage Ah,Al(t+1) */                   \
            _Pragma("unroll")                                                    \
            for (int j = 0; j < 4; j++) {                                        \
                bh[j] = *(const bf16x8*)&SBh[LIDX(RB, wx*64 + j*16 + fr, pcs)];  \
                bl[j] = *(const bf16x8*)&SBl[LIDX(RB, wx*64 + j*16 + fr, pcs)];  \
            }                                                                    \
            bf16x8 x0h = *(const bf16x8*)&SAh[LIDX(RB, wy*128 +   0 + fr, pcs)]; \
            bf16x8 x0l = *(const bf16x8*)&SAl[LIDX(RB, wy*128 +   0 + fr, pcs)]; \
            bf16x8 x1h = *(const bf16x8*)&SAh[LIDX(RB, wy*128 +  16 + fr, pcs)]; \
            bf16x8 x1l = *(const bf16x8*)&SAl[LIDX(RB, wy*128 +  16 + fr, pcs)]; \
            if (pf) {                                                            \
                gload16(Ah + aoff0 + kn, SAh + fpl + d0);                        \
                gload16(Ah + aoff1 + kn, SAh + fpl + d1);                        \
                gload16(Al + aoff0 + kn, SAl + fpl + d0);                        \
                gload16(Al + aoff1 + kn, SAl + fpl + d1);                        \
            }                                                                    \
            __builtin_amdgcn_s_barrier();                                        \
            asm volatile("s_waitcnt lgkmcnt(0)" ::: "memory");                   \
            __builtin_amdgcn_s_setprio(1);                                       \
            QUAD(0, 1, x0h, x0l, x1h, x1l);                                      \
            __builtin_amdgcn_s_setprio(0);                                       \
            __builtin_amdgcn_s_barrier();                                        \
        }                                                                        \
        { /* phase 1: a-quad1 || stage Bh,Bl(t+1) */                             \
            bf16x8 x0h = *(const bf16x8*)&SAh[LIDX(RB, wy*128 +  32 + fr, pcs)]; \
            bf16x8 x0l = *(const bf16x8*)&SAl[LIDX(RB, wy*128 +  32 + fr, pcs)]; \
            bf16x8 x1h = *(const bf16x8*)&SAh[LIDX(RB, wy*128 +  48 + fr, pcs)]; \
            bf16x8 x1l = *(const bf16x8*)&SAl[LIDX(RB, wy*128 +  48 + fr, pcs)]; \
            if (pf) {                                                            \
                gload16(Bh + boff0 + kn, SBh + fpl + d0);                        \
                gload16(Bh + boff1 + kn, SBh + fpl + d1);                        \
                gload16(Bl + boff0 + kn, SBl + fpl + d0);                        \
                gload16(Bl + boff1 + kn, SBl + fpl + d1);                        \
            }                                                                    \
            __builtin_amdgcn_s_barrier();                                        \
            asm volatile("s_waitcnt lgkmcnt(0)" ::: "memory");                   \
            __builtin_amdgcn_s_setprio(1);                                       \
            QUAD(2, 3, x0h, x0l, x1h, x1l);                                      \
            __builtin_amdgcn_s_setprio(0);                                       \
            __builtin_amdgcn_s_barrier();                                        \
        }                                                                        \
        { /* phase 2: a-quad2 */                                                 \
            bf16x8 x0h = *(const bf16x8*)&SAh[LIDX(RB, wy*128 +  64 + fr, pcs)]; \
            bf16x8 x0l = *(const bf16x8*)&SAl[LIDX(RB, wy*128 +  64 + fr, pcs)]; \
            bf16x8 x1h = *(const bf16x8*)&SAh[LIDX(RB, wy*128 +  80 + fr, pcs)]; \
            bf16x8 x1l = *(const bf16x8*)&SAl[LIDX(RB, wy*128 +  80 + fr, pcs)]; \
            __builtin_amdgcn_s_barrier();                                        \
            asm volatile("s_waitcnt lgkmcnt(0)" ::: "memory");                   \
            __builtin_amdgcn_s_setprio(1);                                       \
            QUAD(4, 5, x0h, x0l, x1h, x1l);                                      \
            __builtin_amdgcn_s_setprio(0);                                       \
            __builtin_amdgcn_s_barrier();                                        \
        }                                                                        \
        { /* phase 3: a-quad3, K-tile boundary drain */                          \
            bf16x8 x0h = *(const bf16x8*)&SAh[LIDX(RB, wy*128 +  96 + fr, pcs)]; \
            bf16x8 x0l = *(const bf16x8*)&SAl[LIDX(RB, wy*128 +  96 + fr, pcs)]; \
            bf16x8 x1h = *(const bf16x8*)&SAh[LIDX(RB, wy*128 + 112 + fr, pcs)]; \
            bf16x8 x1l = *(const bf16x8*)&SAl[LIDX(RB, wy*128 + 112 + fr, pcs)]; \
            __builtin_amdgcn_s_barrier();                                        \
            asm volatile("s_waitcnt lgkmcnt(0)" ::: "memory");                   \
            __builtin_amdgcn_s_setprio(1);                                       \
            QUAD(6, 7, x0h, x0l, x1h, x1l);                                      \
            __builtin_amdgcn_s_setprio(0);                                       \
            asm volatile("s_waitcnt vmcnt(0)" ::: "memory");                     \
            __builtin_amdgcn_s_barrier();                                        \
        }                                                                        \
    }

    const int NT = C / 32;    // 16 K-tiles
    #pragma unroll 1
    for (int tt = 0; tt < NT; tt += 2) {
        KBODY(0, tt)
        KBODY(1, tt + 1)
    }
#undef KBODY
#undef QUAD
#undef MFMA1

    // ---- epilogue: overlay sdiag + sred on the (now quiescent) staging LDS ----
    float* sdiag = (float*)smem;                  // 256 floats, 1 KiB
    float* sred  = (float*)(smem + 1024);         // [256][4][2], 8 KiB
    if (tid < 256) sdiag[tid] = diag[bm + tid];
    __syncthreads();

    // C/D layout row=(lane>>4)*4+reg, col=lane&15
    const int quad = lane >> 4;
    #pragma unroll
    for (int i = 0; i < 8; i++) {
        #pragma unroll
        for (int reg = 0; reg < 4; reg++) {
            const int rloc = wy * 128 + i * 16 + quad * 4 + reg;
            const int grow = bm + rloc;
            const float dgv = sdiag[rloc];
            float e = 0.f, cc = 0.f;
            #pragma unroll
            for (int j = 0; j < 4; j++) {
                float s = acc[i][j][reg];
                int gcol = bn + wx * 64 + j * 16 + fr;
                e += __expf(10.f * s - 10.f);
                if (s > dgv && gcol != grow) cc += 1.f;
            }
            for (int o = 1; o < 16; o <<= 1) {
                e += __shfl_xor(e, o);
                cc += __shfl_xor(cc, o);
            }
            if (fr == 0) {
                sred[(rloc * 4 + wx) * 2 + 0] = e;
                sred[(rloc * 4 + wx) * 2 + 1] = cc;
            }
        }
    }
    __syncthreads();
    if (tid < 256) {
        float se = 0.f, sc = 0.f;
        #pragma unroll
        for (int x = 0; x < 4; x++) {
            se += sred[(tid * 4 + x) * 2 + 0];
            sc += sred[(tid * 4 + x) * 2 + 1];
        }
        atomicAdd(&row_e[bm + tid], se);
        atomicAdd(&row_c[bm + tid], sc);
    }
}

// ================= kernel 3: tiny finalization (1 block, 96 KB of L2-hot reads)
__global__ __launch_bounds__(256) void k_fin(
    const float* __restrict__ dv, const float* __restrict__ dt,
    const float* __restrict__ row_ev, const float* __restrict__ row_et,
    const float* __restrict__ row_cv, const float* __restrict__ row_ct,
    const float* __restrict__ colsum, const float* __restrict__ colsq,
    float* __restrict__ out)
{
    const int t = threadIdx.x;
    const int lane = t & 63;
    const int wv = t >> 6;

    float vals[10];
    for (int k = 0; k < 10; k++) vals[k] = 0.f;
    for (int i = 0; i < 16; i++) {
        const int row = i * 256 + t;
        float se = row_ev[row] + row_et[row];
        float pv = row_cv[row];
        float pt = row_ct[row];
        vals[0] += logf(se) + 10.f;
        vals[1] += (pv < 0.5f) ? 1.f : 0.f;
        vals[2] += (pv < 4.5f) ? 1.f : 0.f;
        vals[3] += (pv < 9.5f) ? 1.f : 0.f;
        vals[4] += pv;
        vals[5] += (pt < 0.5f) ? 1.f : 0.f;
        vals[6] += (pt < 4.5f) ? 1.f : 0.f;
        vals[7] += (pt < 9.5f) ? 1.f : 0.f;
        vals[8] += pt;
        vals[9] += __expf(10.f * dv[row] - 10.f) + __expf(10.f * dt[row] - 10.f);
    }
    __shared__ float red[4][10];
    for (int k = 0; k < 10; k++) {
        float v = vals[k];
        for (int o = 1; o < 64; o <<= 1) v += __shfl_xor(v, o);
        if (lane == 0) red[wv][k] = v;
    }

    // stds: each thread handles cols t and t+256 of each matrix
    __shared__ float smat[4][4];
    for (int m = 0; m < 4; m++) {
        float sd2 = 0.f;
        for (int h = 0; h < 2; h++) {
            int c = h * 256 + t;
            float a = colsum[m * 512 + c];
            float q = colsq [m * 512 + c];
            float var = (q - a * a * (1.f / N)) * (1.f / (N - 1));
            sd2 += sqrtf(fmaxf(var, 0.f));
        }
        for (int o = 1; o < 64; o <<= 1) sd2 += __shfl_xor(sd2, o);
        if (lane == 0) smat[wv][m] = sd2;
    }
    __syncthreads();
    if (t == 0) {
        float g[10];
        for (int k = 0; k < 10; k++)
            g[k] = red[0][k] + red[1][k] + red[2][k] + red[3][k];
        float stds[4];
        for (int m = 0; m < 4; m++)
            stds[m] = (smat[0][m] + smat[1][m] + smat[2][m] + smat[3][m]) * (1.f / 512.f);
        const float invN = 1.f / N;
        float nominator = logf(g[9]) + 10.f;
        out[0]  = g[0] * invN - nominator;
        out[1]  = stds[0];
        out[2]  = stds[1];
        out[3]  = stds[2];
        out[4]  = stds[3];
        out[5]  = g[1] * invN;
        out[6]  = g[2] * invN;
        out[7]  = g[3] * invN;
        out[8]  = g[4] * invN;
        out[9]  = g[5] * invN;
        out[10] = g[6] * invN;
        out[11] = g[7] * invN;
        out[12] = g[8] * invN;
    }
}

extern "C" void kernel_launch(void* const* d_in, const int* in_sizes, int n_in,
                              void* d_out, int out_size, void* d_ws, size_t ws_size,
                              hipStream_t stream)
{
    char* p = (char*)d_ws;

    // --- zeroed accumulator region (contiguous, 80 KB) ---
    float* row_ev = (float*)p; p += N * 4;
    float* row_et = (float*)p; p += N * 4;
    float* row_cv = (float*)p; p += N * 4;
    float* row_ct = (float*)p; p += N * 4;
    float* colsum = (float*)p; p += 4 * 512 * 4;
    float* colsq  = (float*)p; p += 4 * 512 * 4;
    const size_t acc_bytes = (size_t)(p - (char*)d_ws);

    // --- plain workspace ---
    const size_t NE = (size_t)N * C;           // 2,097,152 elems
    const long mat_stride = 2 * NE;            // hi + lo, in bf16 elems
    __hip_bfloat16* hiA[4];
    __hip_bfloat16* loA[4];
    for (int m = 0; m < 4; m++) {
        hiA[m] = (__hip_bfloat16*)p; p += NE * 2;
        loA[m] = (__hip_bfloat16*)p; p += NE * 2;
    }
    float* dv = (float*)p; p += N * 4;
    float* dt = (float*)p; p += N * 4;

    hipMemsetAsync(d_ws, 0, acc_bytes, stream);

    // 1. paired single-pass prep: split x4 + diag + col-std atomics
    k_prep<<<dim3(512), 256, 0, stream>>>(
        (const float*)d_in[0], (const float*)d_in[1],
        (const float*)d_in[2], (const float*)d_in[3],
        hiA[0], mat_stride, dv, dt, colsum, colsq);

    // 2. both fused GEMMs in one dispatch (z selects), 256^2 tile, 8 waves
    k_gemm<<<dim3(16, 16, 2), 512, 0, stream>>>(
        hiA[0], loA[0], hiA[1], loA[1], hiA[2], loA[2], hiA[3], loA[3],
        dv, dt, row_ev, row_et, row_cv, row_ct);

    // 3. tiny finalization (single block; inputs are L2-hot)
    k_fin<<<dim3(1), 256, 0, stream>>>(
        dv, dt, row_ev, row_et, row_cv, row_ct, colsum, colsq, (float*)d_out);
}